// Round 4
// baseline (692.021 us; speedup 1.0000x reference)
//
#include <hip/hip_runtime.h>
#include <cstdint>

// AttentionBlock (fp32 I/O), algebraically collapsed:
//  xn = s*x + t (GroupNorm affine per batch/channel)
//  logits = scale*(Wq G Wk^T + aq bk^T + bq (ak + N bk)^T), G from Gx = x x^T
//  attn = softmax(logits);  y = x + Af x + cf 1^T,  Af = (Pw attn Wv) diag(s)
// MFMA kernels use split-bf16 (hi+lo) operands for ~fp32 accuracy.
// fp32 chain scratch lives in d_out front (k_final overwrites it last).
// R1: k_gram atomic-free, private partial tiles, reduction fused into k_G.
// R3: T14 reg-staged prefetch hoist in k_gram (kept).
// R4: k_final = 256m x 64n tile, Af via LDS (copy, no split), x split halved,
//     conflict-free LDS write patterns, prefetch hoist, LB(256,3), 50KB LDS.

typedef unsigned short u16;
typedef unsigned int u32;
typedef __bf16 bf16x8 __attribute__((ext_vector_type(8)));
typedef float f4 __attribute__((ext_vector_type(4)));

#define N_SP 32768
#define C_CH 512
#define NB 2
#define KSPLIT 32
#define LSTR 40   // LDS row stride in u16 (16B-aligned rows, 2-way-max bank aliasing)

__device__ __forceinline__ float b2f(u16 h){
  union { float f; u32 u; } v; v.u = ((u32)h) << 16; return v.f;
}
__device__ __forceinline__ u16 f2b(float f){
  union { float f; u32 u; } v; v.f = f;
  u32 u = v.u;
  return (u16)((u + 0x7fffu + ((u >> 16) & 1u)) >> 16);
}
__device__ __forceinline__ void split(float v, u16& h, u16& l){
  h = f2b(v);
  l = f2b(v - b2f(h));
}

// ---- per-channel sum / sumsq over N_SP (fp32 input) ------------------------
__global__ __launch_bounds__(256) void k_stats(const float* __restrict__ x,
                                               float* __restrict__ cs, float* __restrict__ cq){
  const long bc = blockIdx.x;                 // 0..NB*C_CH-1
  const float* p = x + bc * (long)N_SP;
  const int t = threadIdx.x;
  float s = 0.f, q = 0.f;
  for(int i=0;i<32;i++){
    float4 v = *(const float4*)(p + i*1024 + t*4);
    s += v.x + v.y + v.z + v.w;
    q += v.x*v.x + v.y*v.y + v.z*v.z + v.w*v.w;
  }
  for(int off=32; off; off>>=1){ s += __shfl_down(s, off, 64); q += __shfl_down(q, off, 64); }
  __shared__ float rs[4], rq[4];
  int lane = t & 63, wv = t >> 6;
  if(lane==0){ rs[wv]=s; rq[wv]=q; }
  __syncthreads();
  if(t==0){ cs[bc] = rs[0]+rs[1]+rs[2]+rs[3]; cq[bc] = rq[0]+rq[1]+rq[2]+rq[3]; }
}

// ---- group stats -> per-channel scale/shift + xn row-sums ------------------
__global__ void k_gn(const float* __restrict__ cs, const float* __restrict__ cq,
                     const float* __restrict__ gw, const float* __restrict__ gb,
                     float* __restrict__ s_, float* __restrict__ t_, float* __restrict__ rxn){
  int i = blockIdx.x*blockDim.x + threadIdx.x;
  if(i >= NB*C_CH) return;
  int b = i >> 9, c = i & 511, g = c >> 4;   // 512/32 = 16 channels per group
  int base = (b << 9) | (g << 4);
  float sum=0.f, sq=0.f;
  for(int j=0;j<16;j++){ sum += cs[base+j]; sq += cq[base+j]; }
  const float inv = 1.0f / (16.0f * (float)N_SP);
  float mean = sum * inv;
  float var = sq * inv - mean*mean;
  if(var < 0.f) var = 0.f;
  float rs = rsqrtf(var + 1e-5f);
  float sc = gw[c] * rs;
  float tt = gb[c] - mean * sc;
  s_[i] = sc; t_[i] = tt;
  rxn[i] = sc * cs[i] + (float)N_SP * tt;
}

// ---- Gram partials: Gp[b][tile][ks] = x_tile_i @ x_tile_j^T (no atomics) ---
__global__ __launch_bounds__(256) void k_gram(const float* __restrict__ x, float* __restrict__ Gp){
  __shared__ u16 Ah[128*LSTR], Al[128*LSTR], Bh[128*LSTR], Bl[128*LSTR];
  const int t = threadIdx.x;
  const int tile = blockIdx.x;               // 0..15 : ti*4 + tj
  const int ti = tile >> 2, tj = tile & 3;
  const int b = blockIdx.z;
  const int i0 = ti << 7, j0 = tj << 7;
  const long xb = (long)b * C_CH * (long)N_SP;
  const int k0 = blockIdx.y * (N_SP / KSPLIT);
  const int lane = t & 63, wave = t >> 6;
  const int wm = wave >> 1, wn = wave & 1;
  const int lr = lane & 15, quad = lane >> 4;
  const int srow = t >> 1, skh = (t & 1) << 4;

  f4 acc[4][4];
  for(int i=0;i<4;i++) for(int j=0;j<4;j++){ f4 z = {0.f,0.f,0.f,0.f}; acc[i][j]=z; }

  const float* gi = x + xb + (long)(i0 + srow)*N_SP + k0 + skh;
  const float* gj = x + xb + (long)(j0 + srow)*N_SP + k0 + skh;

  // prologue: tile kk=0 into regs
  float4 va[4], vb[4];
  #pragma unroll
  for(int j2=0;j2<4;j2++){ va[j2] = *(const float4*)(gi + j2*4); vb[j2] = *(const float4*)(gj + j2*4); }

  for(int kk=0; kk<N_SP/KSPLIT; kk+=32){
    // split + LDS write (waits on prefetched regs)
    #pragma unroll
    for(int j2=0;j2<4;j2++){
      float fa[4] = {va[j2].x, va[j2].y, va[j2].z, va[j2].w};
      float fb[4] = {vb[j2].x, vb[j2].y, vb[j2].z, vb[j2].w};
      u16 ha[4], la[4], hb[4], lb[4];
      #pragma unroll
      for(int e=0;e<4;e++){ split(fa[e], ha[e], la[e]); split(fb[e], hb[e], lb[e]); }
      int o = srow*LSTR + skh + j2*4;
      *(uint2*)&Ah[o] = *(uint2*)ha; *(uint2*)&Al[o] = *(uint2*)la;
      *(uint2*)&Bh[o] = *(uint2*)hb; *(uint2*)&Bl[o] = *(uint2*)lb;
    }
    __syncthreads();
    // hoisted prefetch: next tile's loads overlap ds_read+MFMA below
    if(kk + 32 < N_SP/KSPLIT){
      #pragma unroll
      for(int j2=0;j2<4;j2++){
        va[j2] = *(const float4*)(gi + kk + 32 + j2*4);
        vb[j2] = *(const float4*)(gj + kk + 32 + j2*4);
      }
    }
    bf16x8 ah[4], al[4], bh[4], bl[4];
    #pragma unroll
    for(int mt=0; mt<4; mt++){
      int o = (wm*64 + mt*16 + lr)*LSTR + quad*8;
      ah[mt] = *(const bf16x8*)&Ah[o]; al[mt] = *(const bf16x8*)&Al[o];
    }
    #pragma unroll
    for(int nt=0; nt<4; nt++){
      int o = (wn*64 + nt*16 + lr)*LSTR + quad*8;
      bh[nt] = *(const bf16x8*)&Bh[o]; bl[nt] = *(const bf16x8*)&Bl[o];
    }
    #pragma unroll
    for(int mt=0; mt<4; mt++)
      #pragma unroll
      for(int nt=0; nt<4; nt++){
        acc[mt][nt] = __builtin_amdgcn_mfma_f32_16x16x32_bf16(ah[mt], bh[nt], acc[mt][nt], 0, 0, 0);
        acc[mt][nt] = __builtin_amdgcn_mfma_f32_16x16x32_bf16(ah[mt], bl[nt], acc[mt][nt], 0, 0, 0);
        acc[mt][nt] = __builtin_amdgcn_mfma_f32_16x16x32_bf16(al[mt], bh[nt], acc[mt][nt], 0, 0, 0);
      }
    __syncthreads();   // readers done before next write
  }
  // coalesced private-partial store: Gp[((b*16+tile)*KSPLIT+ks)][128][128]
  float* dst = Gp + ((long)(b*16 + tile)*KSPLIT + blockIdx.y) * 16384;
  #pragma unroll
  for(int mt=0; mt<4; mt++){
    #pragma unroll
    for(int nt=0; nt<4; nt++){
      int m = wm*64 + mt*16 + quad*4;
      int n = wn*64 + nt*16 + lr;
      #pragma unroll
      for(int r=0;r<4;r++)
        dst[(m + r)*128 + n] = acc[mt][nt][r];
    }
  }
}

// ---- reduce partials + apply GN affine to Gram -----------------------------
__global__ __launch_bounds__(256) void k_G(const float* __restrict__ Gp, const float* __restrict__ s_,
                                           const float* __restrict__ t_, const float* __restrict__ cs,
                                           float* __restrict__ G){
  long idx4 = ((long)blockIdx.x*256 + threadIdx.x) * 4;   // first of 4 consecutive elements
  int j = (int)(idx4 & 511);
  int i = (int)((idx4 >> 9) & 511);
  int b = (int)(idx4 >> 18);
  int tile = ((i >> 7) << 2) | (j >> 7);
  int il = i & 127, jl = j & 127;
  const float* src = Gp + ((long)(b*16 + tile)*KSPLIT) * 16384 + il*128 + jl;
  float ax=0.f, ay=0.f, az=0.f, aw=0.f;
  #pragma unroll 4
  for(int ks=0; ks<KSPLIT; ks++){
    float4 v = *(const float4*)(src + (long)ks*16384);
    ax += v.x; ay += v.y; az += v.z; aw += v.w;
  }
  long bo = (long)b << 9;
  float si = s_[bo+i], tii = t_[bo+i], csi = cs[bo+i];
  float g[4] = {ax, ay, az, aw};
  float4 out;
  float* po = (float*)&out;
  #pragma unroll
  for(int e=0;e<4;e++){
    int je = j + e;
    float sj = s_[bo+je], tj = t_[bo+je], csj = cs[bo+je];
    po[e] = si*sj*g[e] + si*csi*tj + tii*sj*csj + (float)N_SP*tii*tj;
  }
  *(float4*)&G[idx4] = out;
}

// ---- small fp32 matmuls, 512x512x512, C = A @ B ----------------------------
__global__ __launch_bounds__(256) void k_mm_nn(const float* __restrict__ A, long sA,
                                               const float* __restrict__ B, long sB,
                                               float* __restrict__ C, long sC){
  __shared__ float As_[16][68];
  __shared__ float Bs_[16][68];
  const int b = blockIdx.z;
  A += (long)b*sA; B += (long)b*sB; C += (long)b*sC;
  const int m0 = (blockIdx.x >> 3) << 6;
  const int n0 = (blockIdx.x & 7) << 6;
  const int t = threadIdx.x;
  const int tm = t >> 4, tn = t & 15;
  float acc[4][4] = {};
  const int ar = t >> 2, ac = (t & 3) << 2;
  const int br = t >> 4, bc = (t & 15) << 2;
  for(int k0=0; k0<512; k0+=16){
    float4 av = *(const float4*)&A[(long)(m0 + ar)*512 + k0 + ac];
    float4 bv = *(const float4*)&B[(long)(k0 + br)*512 + n0 + bc];
    __syncthreads();
    As_[ac+0][ar] = av.x; As_[ac+1][ar] = av.y; As_[ac+2][ar] = av.z; As_[ac+3][ar] = av.w;
    *(float4*)&Bs_[br][bc] = bv;
    __syncthreads();
    #pragma unroll
    for(int k=0;k<16;k++){
      float4 a4 = *(const float4*)&As_[k][tm<<2];
      float4 b4 = *(const float4*)&Bs_[k][tn<<2];
      float aa[4] = {a4.x,a4.y,a4.z,a4.w}, bb[4] = {b4.x,b4.y,b4.z,b4.w};
      #pragma unroll
      for(int i=0;i<4;i++)
        #pragma unroll
        for(int j=0;j<4;j++) acc[i][j] += aa[i]*bb[j];
    }
  }
  for(int i=0;i<4;i++) for(int j=0;j<4;j++)
    C[(long)(m0 + (tm<<2) + i)*512 + n0 + (tn<<2) + j] = acc[i][j];
}

// ---- logits: C = scale*(A @ Bn^T + aq bk^T + bq (ak + N bk)^T) -------------
__global__ __launch_bounds__(256) void k_mm_nt_logits(const float* __restrict__ A, long sA,
    const float* __restrict__ Bn, float* __restrict__ C, long sC,
    const float* __restrict__ aq, const float* __restrict__ ak,
    const float* __restrict__ bq, const float* __restrict__ bk, float scale){
  __shared__ float As_[16][68];
  __shared__ float Bs_[16][68];
  const int b = blockIdx.z;
  A += (long)b*sA; C += (long)b*sC;
  const float* aqb = aq + (long)b*512;
  const float* akb = ak + (long)b*512;
  const int m0 = (blockIdx.x >> 3) << 6;
  const int n0 = (blockIdx.x & 7) << 6;
  const int t = threadIdx.x;
  const int tm = t >> 4, tn = t & 15;
  float acc[4][4] = {};
  const int ar = t >> 2, ac = (t & 3) << 2;
  for(int k0=0; k0<512; k0+=16){
    float4 av = *(const float4*)&A[(long)(m0 + ar)*512 + k0 + ac];
    float4 bv = *(const float4*)&Bn[(long)(n0 + ar)*512 + k0 + ac];
    __syncthreads();
    As_[ac+0][ar] = av.x; As_[ac+1][ar] = av.y; As_[ac+2][ar] = av.z; As_[ac+3][ar] = av.w;
    Bs_[ac+0][ar] = bv.x; Bs_[ac+1][ar] = bv.y; Bs_[ac+2][ar] = bv.z; Bs_[ac+3][ar] = bv.w;
    __syncthreads();
    #pragma unroll
    for(int k=0;k<16;k++){
      float4 a4 = *(const float4*)&As_[k][tm<<2];
      float4 b4 = *(const float4*)&Bs_[k][tn<<2];
      float aa[4] = {a4.x,a4.y,a4.z,a4.w}, bb[4] = {b4.x,b4.y,b4.z,b4.w};
      #pragma unroll
      for(int i=0;i<4;i++)
        #pragma unroll
        for(int j=0;j<4;j++) acc[i][j] += aa[i]*bb[j];
    }
  }
  for(int i=0;i<4;i++) for(int j=0;j<4;j++){
    int gi = m0 + (tm<<2) + i, gj = n0 + (tn<<2) + j;
    float vv = acc[i][j] + aqb[gi]*bk[gj] + bq[gi]*(akb[gj] + (float)N_SP*bk[gj]);
    C[(long)gi*512 + gj] = scale*vv;
  }
}

// ---- row softmax over 512 --------------------------------------------------
__global__ __launch_bounds__(256) void k_softmax(float* __restrict__ L){
  const long row = blockIdx.x;
  float* p = L + row*512;
  const int t = threadIdx.x;
  float v0 = p[t], v1 = p[t+256];
  float m = fmaxf(v0, v1);
  for(int off=32; off; off>>=1) m = fmaxf(m, __shfl_down(m, off, 64));
  __shared__ float red[4], red2[4];
  int lane = t & 63, wv = t >> 6;
  if(lane==0) red[wv] = m;
  __syncthreads();
  float M = fmaxf(fmaxf(red[0],red[1]), fmaxf(red[2],red[3]));
  float e0 = __expf(v0 - M), e1 = __expf(v1 - M);
  float s = e0 + e1;
  for(int off=32; off; off>>=1) s += __shfl_down(s, off, 64);
  if(lane==0) red2[wv] = s;
  __syncthreads();
  float inv = 1.0f / (red2[0]+red2[1]+red2[2]+red2[3]);
  p[t] = e0*inv; p[t+256] = e1*inv;
}

// ---- out[b,i] = M[b] row_i . v[b] (+ addv) (+= out) ------------------------
__global__ __launch_bounds__(128) void k_rowdot(const float* __restrict__ M, long sM,
    const float* __restrict__ v, long sv, float* __restrict__ out, long sout,
    const float* __restrict__ addv, long saddv, int accum){
  const int i = blockIdx.x, b = blockIdx.y;
  const float* Mr = M + (long)b*sM + (long)i*512;
  const float* vb = v + (long)b*sv;
  const int t = threadIdx.x;
  float s = Mr[t]*vb[t] + Mr[t+128]*vb[t+128] + Mr[t+256]*vb[t+256] + Mr[t+384]*vb[t+384];
  for(int off=32; off; off>>=1) s += __shfl_down(s, off, 64);
  __shared__ float r2[2];
  if((t&63)==0) r2[t>>6] = s;
  __syncthreads();
  if(t==0){
    float r = r2[0] + r2[1];
    long oi = (long)b*sout + i;
    if(addv) r += addv[(long)b*saddv + i];
    if(accum) r += out[oi];
    out[oi] = r;
  }
}

// ---- Af = AM * diag(s) split to bf16 hi/lo --------------------------------
__global__ void k_af(const float* __restrict__ A, const float* __restrict__ s_,
                     u16* __restrict__ Afh, u16* __restrict__ Afl){
  long idx = (long)blockIdx.x*256 + threadIdx.x;
  int k = idx & 511; long b = idx >> 18;
  float vv = A[idx] * s_[(b<<9) + k];
  u16 h, l; split(vv, h, l);
  Afh[idx] = h; Afl[idx] = l;
}

// ---- final: y = x + Af @ x + cf 1^T ----------------------------------------
// 256m x 64n tile, 4 waves stacked in m (each 64m x 64n). Af staged via LDS
// (pure copy, pre-split); x staged+split (8 splits/thread/iter). Reg-staged
// prefetch hoist. Conflict-free LDS write patterns. 50 KB LDS, 3 blocks/CU.
__global__ __launch_bounds__(256, 3) void k_final(const u16* __restrict__ Afh, const u16* __restrict__ Afl,
                                                  const float* __restrict__ x, const float* __restrict__ cf,
                                                  float* __restrict__ y){
  __shared__ u16 Ah[256*LSTR], Al[256*LSTR], Bh[64*LSTR], Bl[64*LSTR];
  const int t = threadIdx.x;
  const int b = blockIdx.z;
  const int n0 = blockIdx.x << 6;          // 64-wide n strip
  const int m0 = blockIdx.y << 8;          // 256-row m block
  const int lane = t & 63, wave = t >> 6;
  const int lr = lane & 15, quad = lane >> 4;
  const int mw = wave << 6;                // wave's m base within block
  // B staging: x[k][n] fp32 -> Bs[n][k] hi/lo; thread owns k-pair x 4n
  const int kp = (t & 15) << 1;            // k row pair 0..30
  const int nq = (t >> 4) << 2;            // n group 0..60 (320B LDS stride -> 2-way max)
  const long xb = (long)b*C_CH*(long)N_SP;
  const long afb = (long)b*C_CH*C_CH;

  f4 acc[4][4];
  for(int i=0;i<4;i++) for(int j=0;j<4;j++){ f4 z = {0.f,0.f,0.f,0.f}; acc[i][j]=z; }

  // A staging: thread t owns row m0+t, 32 k per iter (hi+lo, pure copy)
  const u16* gah = Afh + afb + (long)(m0 + t)*C_CH;
  const u16* gal = Afl + afb + (long)(m0 + t)*C_CH;

  // prologue: kk=0 into regs
  uint4 sa0 = *(const uint4*)(gah);      uint4 sa1 = *(const uint4*)(gah + 8);
  uint4 sa2 = *(const uint4*)(gah + 16); uint4 sa3 = *(const uint4*)(gah + 24);
  uint4 sl0 = *(const uint4*)(gal);      uint4 sl1 = *(const uint4*)(gal + 8);
  uint4 sl2 = *(const uint4*)(gal + 16); uint4 sl3 = *(const uint4*)(gal + 24);
  const float* gx0 = x + xb + (long)kp*N_SP + n0 + nq;
  float4 vx0 = *(const float4*)(gx0);
  float4 vx1 = *(const float4*)(gx0 + N_SP);

  for(int kk=0; kk<C_CH; kk+=32){
    // stage A (copy; row t at stride 80B -> uniform bank use)
    int ao = t*LSTR;
    *(uint4*)&Ah[ao] = sa0; *(uint4*)&Ah[ao+8] = sa1; *(uint4*)&Ah[ao+16] = sa2; *(uint4*)&Ah[ao+24] = sa3;
    *(uint4*)&Al[ao] = sl0; *(uint4*)&Al[ao+8] = sl1; *(uint4*)&Al[ao+16] = sl2; *(uint4*)&Al[ao+24] = sl3;
    // stage B (split x)
    float f0[4] = {vx0.x, vx0.y, vx0.z, vx0.w};
    float f1[4] = {vx1.x, vx1.y, vx1.z, vx1.w};
    #pragma unroll
    for(int j=0;j<4;j++){
      u16 h0,l0,h1,l1;
      split(f0[j], h0, l0); split(f1[j], h1, l1);
      int o = (nq + j)*LSTR + kp;
      *(u32*)&Bh[o] = (u32)h0 | ((u32)h1 << 16);
      *(u32*)&Bl[o] = (u32)l0 | ((u32)l1 << 16);
    }
    __syncthreads();
    // hoisted prefetch of next k-tile: overlaps ds_read + MFMA below
    if(kk + 32 < C_CH){
      const u16* ga2 = gah + kk + 32;
      const u16* gl2 = gal + kk + 32;
      sa0 = *(const uint4*)(ga2);      sa1 = *(const uint4*)(ga2 + 8);
      sa2 = *(const uint4*)(ga2 + 16); sa3 = *(const uint4*)(ga2 + 24);
      sl0 = *(const uint4*)(gl2);      sl1 = *(const uint4*)(gl2 + 8);
      sl2 = *(const uint4*)(gl2 + 16); sl3 = *(const uint4*)(gl2 + 24);
      const float* gxn = x + xb + (long)(kk + 32 + kp)*N_SP + n0 + nq;
      vx0 = *(const float4*)(gxn);
      vx1 = *(const float4*)(gxn + N_SP);
    }
    bf16x8 bh[4], bl[4];
    #pragma unroll
    for(int nt=0; nt<4; nt++){
      int o = (nt*16 + lr)*LSTR + quad*8;
      bh[nt] = *(const bf16x8*)&Bh[o]; bl[nt] = *(const bf16x8*)&Bl[o];
    }
    #pragma unroll
    for(int mt=0; mt<4; mt++){
      int o = (mw + mt*16 + lr)*LSTR + quad*8;
      bf16x8 ah = *(const bf16x8*)&Ah[o];
      bf16x8 al = *(const bf16x8*)&Al[o];
      #pragma unroll
      for(int nt=0; nt<4; nt++){
        acc[mt][nt] = __builtin_amdgcn_mfma_f32_16x16x32_bf16(ah, bh[nt], acc[mt][nt], 0, 0, 0);
        acc[mt][nt] = __builtin_amdgcn_mfma_f32_16x16x32_bf16(ah, bl[nt], acc[mt][nt], 0, 0, 0);
        acc[mt][nt] = __builtin_amdgcn_mfma_f32_16x16x32_bf16(al, bh[nt], acc[mt][nt], 0, 0, 0);
      }
    }
    __syncthreads();   // readers done before next write
  }
  #pragma unroll
  for(int mt=0; mt<4; mt++){
    int mbase = m0 + mw + mt*16 + quad*4;
    float cfv[4];
    #pragma unroll
    for(int r=0;r<4;r++) cfv[r] = cf[b*C_CH + mbase + r];
    #pragma unroll
    for(int nt=0; nt<4; nt++){
      int n = n0 + nt*16 + lr;
      #pragma unroll
      for(int r=0;r<4;r++){
        long idx = xb + (long)(mbase + r)*N_SP + n;
        y[idx] = acc[mt][nt][r] + x[idx] + cfv[r];
      }
    }
  }
}

extern "C" void kernel_launch(void* const* d_in, const int* in_sizes, int n_in,
                              void* d_out, int out_size, void* d_ws, size_t ws_size,
                              hipStream_t stream){
  const float* x    = (const float*)d_in[0];
  const float* gnw  = (const float*)d_in[1];
  const float* gnb  = (const float*)d_in[2];
  const float* qkvw = (const float*)d_in[3];
  const float* qkvb = (const float*)d_in[4];
  const float* pw   = (const float*)d_in[5];
  const float* pb   = (const float*)d_in[6];
  float* y = (float*)d_out;

  // --- scratch region A: front of d_out (chain done before k_final) --------
  char* w = (char*)d_out;
  size_t off = 0;
  auto alloc = [&](size_t bytes)->void*{
    void* p = w + off; off = (off + bytes + 255) & ~(size_t)255; return p;
  };
  float* GP   = (float*)alloc((size_t)NB*16*KSPLIT*16384*4); // 64 MB partial tiles
  float* G    = (float*)alloc((size_t)NB*C_CH*C_CH*4);
  float* T1   = (float*)alloc((size_t)NB*C_CH*C_CH*4);
  float* ATT  = (float*)alloc((size_t)NB*C_CH*C_CH*4);
  float* M0   = (float*)alloc((size_t)NB*C_CH*C_CH*4);
  float* AM   = (float*)alloc((size_t)NB*C_CH*C_CH*4);
  // 64 MB + ~10 MB << 128 MB d_out

  // --- scratch region B: d_ws — only what k_final reads (~2.2 MB) ----------
  char* w2 = (char*)d_ws;
  size_t off2 = 0;
  auto alloc2 = [&](size_t bytes)->void*{
    void* p = w2 + off2; off2 = (off2 + bytes + 255) & ~(size_t)255; return p;
  };
  u16*   AFH  = (u16*)  alloc2((size_t)NB*C_CH*C_CH*2);  // 1 MB
  u16*   AFL  = (u16*)  alloc2((size_t)NB*C_CH*C_CH*2);  // 1 MB
  float* CF   = (float*)alloc2(NB*C_CH*4);
  float* CS   = (float*)alloc2(NB*C_CH*4);
  float* CQ   = (float*)alloc2(NB*C_CH*4);
  float* S_   = (float*)alloc2(NB*C_CH*4);
  float* T_   = (float*)alloc2(NB*C_CH*4);
  float* RXN  = (float*)alloc2(NB*C_CH*4);
  float* AQ   = (float*)alloc2(NB*C_CH*4);
  float* AK   = (float*)alloc2(NB*C_CH*4);
  float* E    = (float*)alloc2(NB*C_CH*4);
  (void)ws_size; (void)in_sizes; (void)n_in; (void)out_size;

  const float scale = 0.04419417382415922f; // 1/sqrt(512)

  k_stats<<<NB*C_CH, 256, 0, stream>>>(x, CS, CQ);
  k_gn<<<4, 256, 0, stream>>>(CS, CQ, gnw, gnb, S_, T_, RXN);
  k_gram<<<dim3(16, KSPLIT, NB), 256, 0, stream>>>(x, GP);
  k_G<<<512, 256, 0, stream>>>(GP, S_, T_, CS, G);
  k_mm_nn<<<dim3(64,1,NB), 256, 0, stream>>>(qkvw, 0, G, 262144, T1, 262144);
  k_rowdot<<<dim3(512,NB), 128, 0, stream>>>(qkvw,          0, RXN, 512, AQ, 512, nullptr, 0, 0);
  k_rowdot<<<dim3(512,NB), 128, 0, stream>>>(qkvw+262144,   0, RXN, 512, AK, 512, nullptr, 0, 0);
  k_mm_nt_logits<<<dim3(64,1,NB), 256, 0, stream>>>(T1, 262144, qkvw+262144, ATT, 262144,
                                                    AQ, AK, qkvb, qkvb+512, scale);
  k_softmax<<<NB*C_CH, 256, 0, stream>>>(ATT);
  k_rowdot<<<dim3(512,NB), 128, 0, stream>>>(ATT, 262144, qkvb+1024, 0, E, 512, nullptr, 0, 0);
  k_mm_nn<<<dim3(64,1,NB), 256, 0, stream>>>(ATT, 262144, qkvw+524288, 0, M0, 262144);
  k_mm_nn<<<dim3(64,1,NB), 256, 0, stream>>>(pw, 0, M0, 262144, AM, 262144);
  k_rowdot<<<dim3(512,NB), 128, 0, stream>>>(AM, 262144, T_, 512, CF, 512, nullptr, 0, 0);
  k_rowdot<<<dim3(512,NB), 128, 0, stream>>>(pw, 0, E, 512, CF, 512, pb, 0, 1);
  k_af<<<(NB*C_CH*C_CH)/256, 256, 0, stream>>>(AM, S_, AFH, AFL);
  k_final<<<dim3(N_SP/64, C_CH/256, NB), 256, 0, stream>>>(AFH, AFL, x, CF, y);
}

// Round 7
// 613.888 us; speedup vs baseline: 1.1273x; 1.1273x over previous
//
#include <hip/hip_runtime.h>
#include <cstdint>

// AttentionBlock (fp32 I/O), algebraically collapsed:
//  xn = s*x + t (GroupNorm affine per batch/channel)
//  logits = scale*(Wq G Wk^T + aq bk^T + bq (ak + N bk)^T), G from Gx = x x^T
//  attn = softmax(logits);  y = x + Af x + cf 1^T,  Af = (Pw attn Wv) diag(s)
// k_gram uses split-bf16 (hi+lo, 3 products) — K=32768 demands ~2^-16 rel err.
// k_final uses SINGLE fp16 product — K=512, |Af|~0.05: err ~1e-3 << budget.
// R1: k_gram atomic-free, private partial tiles, reduction fused into k_G.
// R3: T14 reg-staged prefetch hoist in k_gram (kept).
// R5: k_final fp16 single-product. FAILED: A-stage covered only 16/32 k-cols.
// R6: fix = two uint4 per thread (exact R2 coverage).
// R7: identical resubmit (R6 bench was an infra flake; kernel never measured).

typedef unsigned short u16;
typedef unsigned int u32;
typedef __bf16 bf16x8 __attribute__((ext_vector_type(8)));
typedef _Float16 f16x8 __attribute__((ext_vector_type(8)));
typedef float f4 __attribute__((ext_vector_type(4)));

#define N_SP 32768
#define C_CH 512
#define NB 2
#define KSPLIT 32
#define LSTR 40   // LDS row stride in u16 (16B-aligned rows)

__device__ __forceinline__ float b2f(u16 h){
  union { float f; u32 u; } v; v.u = ((u32)h) << 16; return v.f;
}
__device__ __forceinline__ u16 f2b(float f){
  union { float f; u32 u; } v; v.f = f;
  u32 u = v.u;
  return (u16)((u + 0x7fffu + ((u >> 16) & 1u)) >> 16);
}
__device__ __forceinline__ void split(float v, u16& h, u16& l){
  h = f2b(v);
  l = f2b(v - b2f(h));
}
__device__ __forceinline__ u16 f2h(float f){
  _Float16 h = (_Float16)f;
  union { _Float16 h; u16 u; } v; v.h = h; return v.u;
}

// ---- per-channel sum / sumsq over N_SP (fp32 input) ------------------------
__global__ __launch_bounds__(256) void k_stats(const float* __restrict__ x,
                                               float* __restrict__ cs, float* __restrict__ cq){
  const long bc = blockIdx.x;                 // 0..NB*C_CH-1
  const float* p = x + bc * (long)N_SP;
  const int t = threadIdx.x;
  float s = 0.f, q = 0.f;
  for(int i=0;i<32;i++){
    float4 v = *(const float4*)(p + i*1024 + t*4);
    s += v.x + v.y + v.z + v.w;
    q += v.x*v.x + v.y*v.y + v.z*v.z + v.w*v.w;
  }
  for(int off=32; off; off>>=1){ s += __shfl_down(s, off, 64); q += __shfl_down(q, off, 64); }
  __shared__ float rs[4], rq[4];
  int lane = t & 63, wv = t >> 6;
  if(lane==0){ rs[wv]=s; rq[wv]=q; }
  __syncthreads();
  if(t==0){ cs[bc] = rs[0]+rs[1]+rs[2]+rs[3]; cq[bc] = rq[0]+rq[1]+rq[2]+rq[3]; }
}

// ---- group stats -> per-channel scale/shift + xn row-sums ------------------
__global__ void k_gn(const float* __restrict__ cs, const float* __restrict__ cq,
                     const float* __restrict__ gw, const float* __restrict__ gb,
                     float* __restrict__ s_, float* __restrict__ t_, float* __restrict__ rxn){
  int i = blockIdx.x*blockDim.x + threadIdx.x;
  if(i >= NB*C_CH) return;
  int b = i >> 9, c = i & 511, g = c >> 4;   // 512/32 = 16 channels per group
  int base = (b << 9) | (g << 4);
  float sum=0.f, sq=0.f;
  for(int j=0;j<16;j++){ sum += cs[base+j]; sq += cq[base+j]; }
  const float inv = 1.0f / (16.0f * (float)N_SP);
  float mean = sum * inv;
  float var = sq * inv - mean*mean;
  if(var < 0.f) var = 0.f;
  float rs = rsqrtf(var + 1e-5f);
  float sc = gw[c] * rs;
  float tt = gb[c] - mean * sc;
  s_[i] = sc; t_[i] = tt;
  rxn[i] = sc * cs[i] + (float)N_SP * tt;
}

// ---- Gram partials: Gp[b][tile][ks] = x_tile_i @ x_tile_j^T (no atomics) ---
__global__ __launch_bounds__(256) void k_gram(const float* __restrict__ x, float* __restrict__ Gp){
  __shared__ u16 Ah[128*LSTR], Al[128*LSTR], Bh[128*LSTR], Bl[128*LSTR];
  const int t = threadIdx.x;
  const int tile = blockIdx.x;               // 0..15 : ti*4 + tj
  const int ti = tile >> 2, tj = tile & 3;
  const int b = blockIdx.z;
  const int i0 = ti << 7, j0 = tj << 7;
  const long xb = (long)b * C_CH * (long)N_SP;
  const int k0 = blockIdx.y * (N_SP / KSPLIT);
  const int lane = t & 63, wave = t >> 6;
  const int wm = wave >> 1, wn = wave & 1;
  const int lr = lane & 15, quad = lane >> 4;
  const int srow = t >> 1, skh = (t & 1) << 4;

  f4 acc[4][4];
  for(int i=0;i<4;i++) for(int j=0;j<4;j++){ f4 z = {0.f,0.f,0.f,0.f}; acc[i][j]=z; }

  const float* gi = x + xb + (long)(i0 + srow)*N_SP + k0 + skh;
  const float* gj = x + xb + (long)(j0 + srow)*N_SP + k0 + skh;

  // prologue: tile kk=0 into regs
  float4 va[4], vb[4];
  #pragma unroll
  for(int j2=0;j2<4;j2++){ va[j2] = *(const float4*)(gi + j2*4); vb[j2] = *(const float4*)(gj + j2*4); }

  for(int kk=0; kk<N_SP/KSPLIT; kk+=32){
    // split + LDS write (waits on prefetched regs)
    #pragma unroll
    for(int j2=0;j2<4;j2++){
      float fa[4] = {va[j2].x, va[j2].y, va[j2].z, va[j2].w};
      float fb[4] = {vb[j2].x, vb[j2].y, vb[j2].z, vb[j2].w};
      u16 ha[4], la[4], hb[4], lb[4];
      #pragma unroll
      for(int e=0;e<4;e++){ split(fa[e], ha[e], la[e]); split(fb[e], hb[e], lb[e]); }
      int o = srow*LSTR + skh + j2*4;
      *(uint2*)&Ah[o] = *(uint2*)ha; *(uint2*)&Al[o] = *(uint2*)la;
      *(uint2*)&Bh[o] = *(uint2*)hb; *(uint2*)&Bl[o] = *(uint2*)lb;
    }
    __syncthreads();
    // hoisted prefetch: next tile's loads overlap ds_read+MFMA below
    if(kk + 32 < N_SP/KSPLIT){
      #pragma unroll
      for(int j2=0;j2<4;j2++){
        va[j2] = *(const float4*)(gi + kk + 32 + j2*4);
        vb[j2] = *(const float4*)(gj + kk + 32 + j2*4);
      }
    }
    bf16x8 ah[4], al[4], bh[4], bl[4];
    #pragma unroll
    for(int mt=0; mt<4; mt++){
      int o = (wm*64 + mt*16 + lr)*LSTR + quad*8;
      ah[mt] = *(const bf16x8*)&Ah[o]; al[mt] = *(const bf16x8*)&Al[o];
    }
    #pragma unroll
    for(int nt=0; nt<4; nt++){
      int o = (wn*64 + nt*16 + lr)*LSTR + quad*8;
      bh[nt] = *(const bf16x8*)&Bh[o]; bl[nt] = *(const bf16x8*)&Bl[o];
    }
    #pragma unroll
    for(int mt=0; mt<4; mt++)
      #pragma unroll
      for(int nt=0; nt<4; nt++){
        acc[mt][nt] = __builtin_amdgcn_mfma_f32_16x16x32_bf16(ah[mt], bh[nt], acc[mt][nt], 0, 0, 0);
        acc[mt][nt] = __builtin_amdgcn_mfma_f32_16x16x32_bf16(ah[mt], bl[nt], acc[mt][nt], 0, 0, 0);
        acc[mt][nt] = __builtin_amdgcn_mfma_f32_16x16x32_bf16(al[mt], bh[nt], acc[mt][nt], 0, 0, 0);
      }
    __syncthreads();   // readers done before next write
  }
  // coalesced private-partial store: Gp[((b*16+tile)*KSPLIT+ks)][128][128]
  float* dst = Gp + ((long)(b*16 + tile)*KSPLIT + blockIdx.y) * 16384;
  #pragma unroll
  for(int mt=0; mt<4; mt++){
    #pragma unroll
    for(int nt=0; nt<4; nt++){
      int m = wm*64 + mt*16 + quad*4;
      int n = wn*64 + nt*16 + lr;
      #pragma unroll
      for(int r=0;r<4;r++)
        dst[(m + r)*128 + n] = acc[mt][nt][r];
    }
  }
}

// ---- reduce partials + apply GN affine to Gram -----------------------------
__global__ __launch_bounds__(256) void k_G(const float* __restrict__ Gp, const float* __restrict__ s_,
                                           const float* __restrict__ t_, const float* __restrict__ cs,
                                           float* __restrict__ G){
  long idx4 = ((long)blockIdx.x*256 + threadIdx.x) * 4;   // first of 4 consecutive elements
  int j = (int)(idx4 & 511);
  int i = (int)((idx4 >> 9) & 511);
  int b = (int)(idx4 >> 18);
  int tile = ((i >> 7) << 2) | (j >> 7);
  int il = i & 127, jl = j & 127;
  const float* src = Gp + ((long)(b*16 + tile)*KSPLIT) * 16384 + il*128 + jl;
  float ax=0.f, ay=0.f, az=0.f, aw=0.f;
  #pragma unroll 4
  for(int ks=0; ks<KSPLIT; ks++){
    float4 v = *(const float4*)(src + (long)ks*16384);
    ax += v.x; ay += v.y; az += v.z; aw += v.w;
  }
  long bo = (long)b << 9;
  float si = s_[bo+i], tii = t_[bo+i], csi = cs[bo+i];
  float g[4] = {ax, ay, az, aw};
  float4 out;
  float* po = (float*)&out;
  #pragma unroll
  for(int e=0;e<4;e++){
    int je = j + e;
    float sj = s_[bo+je], tj = t_[bo+je], csj = cs[bo+je];
    po[e] = si*sj*g[e] + si*csi*tj + tii*sj*csj + (float)N_SP*tii*tj;
  }
  *(float4*)&G[idx4] = out;
}

// ---- small fp32 matmuls, 512x512x512, C = A @ B ----------------------------
__global__ __launch_bounds__(256) void k_mm_nn(const float* __restrict__ A, long sA,
                                               const float* __restrict__ B, long sB,
                                               float* __restrict__ C, long sC){
  __shared__ float As_[16][68];
  __shared__ float Bs_[16][68];
  const int b = blockIdx.z;
  A += (long)b*sA; B += (long)b*sB; C += (long)b*sC;
  const int m0 = (blockIdx.x >> 3) << 6;
  const int n0 = (blockIdx.x & 7) << 6;
  const int t = threadIdx.x;
  const int tm = t >> 4, tn = t & 15;
  float acc[4][4] = {};
  const int ar = t >> 2, ac = (t & 3) << 2;
  const int br = t >> 4, bc = (t & 15) << 2;
  for(int k0=0; k0<512; k0+=16){
    float4 av = *(const float4*)&A[(long)(m0 + ar)*512 + k0 + ac];
    float4 bv = *(const float4*)&B[(long)(k0 + br)*512 + n0 + bc];
    __syncthreads();
    As_[ac+0][ar] = av.x; As_[ac+1][ar] = av.y; As_[ac+2][ar] = av.z; As_[ac+3][ar] = av.w;
    *(float4*)&Bs_[br][bc] = bv;
    __syncthreads();
    #pragma unroll
    for(int k=0;k<16;k++){
      float4 a4 = *(const float4*)&As_[k][tm<<2];
      float4 b4 = *(const float4*)&Bs_[k][tn<<2];
      float aa[4] = {a4.x,a4.y,a4.z,a4.w}, bb[4] = {b4.x,b4.y,b4.z,b4.w};
      #pragma unroll
      for(int i=0;i<4;i++)
        #pragma unroll
        for(int j=0;j<4;j++) acc[i][j] += aa[i]*bb[j];
    }
  }
  for(int i=0;i<4;i++) for(int j=0;j<4;j++)
    C[(long)(m0 + (tm<<2) + i)*512 + n0 + (tn<<2) + j] = acc[i][j];
}

// ---- logits: C = scale*(A @ Bn^T + aq bk^T + bq (ak + N bk)^T) -------------
__global__ __launch_bounds__(256) void k_mm_nt_logits(const float* __restrict__ A, long sA,
    const float* __restrict__ Bn, float* __restrict__ C, long sC,
    const float* __restrict__ aq, const float* __restrict__ ak,
    const float* __restrict__ bq, const float* __restrict__ bk, float scale){
  __shared__ float As_[16][68];
  __shared__ float Bs_[16][68];
  const int b = blockIdx.z;
  A += (long)b*sA; C += (long)b*sC;
  const float* aqb = aq + (long)b*512;
  const float* akb = ak + (long)b*512;
  const int m0 = (blockIdx.x >> 3) << 6;
  const int n0 = (blockIdx.x & 7) << 6;
  const int t = threadIdx.x;
  const int tm = t >> 4, tn = t & 15;
  float acc[4][4] = {};
  const int ar = t >> 2, ac = (t & 3) << 2;
  for(int k0=0; k0<512; k0+=16){
    float4 av = *(const float4*)&A[(long)(m0 + ar)*512 + k0 + ac];
    float4 bv = *(const float4*)&Bn[(long)(n0 + ar)*512 + k0 + ac];
    __syncthreads();
    As_[ac+0][ar] = av.x; As_[ac+1][ar] = av.y; As_[ac+2][ar] = av.z; As_[ac+3][ar] = av.w;
    Bs_[ac+0][ar] = bv.x; Bs_[ac+1][ar] = bv.y; Bs_[ac+2][ar] = bv.z; Bs_[ac+3][ar] = bv.w;
    __syncthreads();
    #pragma unroll
    for(int k=0;k<16;k++){
      float4 a4 = *(const float4*)&As_[k][tm<<2];
      float4 b4 = *(const float4*)&Bs_[k][tn<<2];
      float aa[4] = {a4.x,a4.y,a4.z,a4.w}, bb[4] = {b4.x,b4.y,b4.z,b4.w};
      #pragma unroll
      for(int i=0;i<4;i++)
        #pragma unroll
        for(int j=0;j<4;j++) acc[i][j] += aa[i]*bb[j];
    }
  }
  for(int i=0;i<4;i++) for(int j=0;j<4;j++){
    int gi = m0 + (tm<<2) + i, gj = n0 + (tn<<2) + j;
    float vv = acc[i][j] + aqb[gi]*bk[gj] + bq[gi]*(akb[gj] + (float)N_SP*bk[gj]);
    C[(long)gi*512 + gj] = scale*vv;
  }
}

// ---- row softmax over 512 --------------------------------------------------
__global__ __launch_bounds__(256) void k_softmax(float* __restrict__ L){
  const long row = blockIdx.x;
  float* p = L + row*512;
  const int t = threadIdx.x;
  float v0 = p[t], v1 = p[t+256];
  float m = fmaxf(v0, v1);
  for(int off=32; off; off>>=1) m = fmaxf(m, __shfl_down(m, off, 64));
  __shared__ float red[4], red2[4];
  int lane = t & 63, wv = t >> 6;
  if(lane==0) red[wv] = m;
  __syncthreads();
  float M = fmaxf(fmaxf(red[0],red[1]), fmaxf(red[2],red[3]));
  float e0 = __expf(v0 - M), e1 = __expf(v1 - M);
  float s = e0 + e1;
  for(int off=32; off; off>>=1) s += __shfl_down(s, off, 64);
  if(lane==0) red2[wv] = s;
  __syncthreads();
  float inv = 1.0f / (red2[0]+red2[1]+red2[2]+red2[3]);
  p[t] = e0*inv; p[t+256] = e1*inv;
}

// ---- out[b,i] = M[b] row_i . v[b] (+ addv) (+= out) ------------------------
__global__ __launch_bounds__(128) void k_rowdot(const float* __restrict__ M, long sM,
    const float* __restrict__ v, long sv, float* __restrict__ out, long sout,
    const float* __restrict__ addv, long saddv, int accum){
  const int i = blockIdx.x, b = blockIdx.y;
  const float* Mr = M + (long)b*sM + (long)i*512;
  const float* vb = v + (long)b*sv;
  const int t = threadIdx.x;
  float s = Mr[t]*vb[t] + Mr[t+128]*vb[t+128] + Mr[t+256]*vb[t+256] + Mr[t+384]*vb[t+384];
  for(int off=32; off; off>>=1) s += __shfl_down(s, off, 64);
  __shared__ float r2[2];
  if((t&63)==0) r2[t>>6] = s;
  __syncthreads();
  if(t==0){
    float r = r2[0] + r2[1];
    long oi = (long)b*sout + i;
    if(addv) r += addv[(long)b*saddv + i];
    if(accum) r += out[oi];
    out[oi] = r;
  }
}

// ---- Af = AM * diag(s) -> fp16 ---------------------------------------------
__global__ void k_af(const float* __restrict__ A, const float* __restrict__ s_,
                     u16* __restrict__ Af16){
  long idx = (long)blockIdx.x*256 + threadIdx.x;
  int k = idx & 511; long b = idx >> 18;
  float vv = A[idx] * s_[(b<<9) + k];
  Af16[idx] = f2h(vv);
}

// ---- final: y = x + Af @ x + cf 1^T  (single fp16 product, K=512) ----------
// 128x128 tile, 2x2 waves. Coalesced pairwise A loads (2 threads/row, 16 u16
// each = full 32-col tile). x converted to fp16 on the fly. Prefetch hoist.
__global__ __launch_bounds__(256) void k_final(const u16* __restrict__ Af16,
                                               const float* __restrict__ x, const float* __restrict__ cf,
                                               float* __restrict__ y){
  __shared__ u16 As[128*LSTR], Bs[128*LSTR];
  const int t = threadIdx.x;
  const int b = blockIdx.z;
  const int n0 = blockIdx.x << 7;
  const int m0 = blockIdx.y << 7;
  const int lane = t & 63, wave = t >> 6;
  const int wm = wave >> 1, wn = wave & 1;
  const int lr = lane & 15, quad = lane >> 4;
  // A staging: 2 threads/row; each covers 16 u16 (two uint4) -> 32 cols/row
  const int arow = t >> 1, akh = (t & 1) << 4;
  const long afb = (long)b*C_CH*C_CH;
  // B staging: thread owns k-pair (kp,kp+1) x 8 n
  const int kp = (t & 15) << 1;   // k row pair 0..30
  const int nq = (t >> 4) << 3;   // n group 0..120
  const long xb = (long)b*C_CH*(long)N_SP;

  f4 acc[4][4];
  for(int i=0;i<4;i++) for(int j=0;j<4;j++){ f4 z = {0.f,0.f,0.f,0.f}; acc[i][j]=z; }

  const u16* gah = Af16 + afb + (long)(m0 + arow)*C_CH + akh;
  // prologue: kk=0 into regs
  uint4 vah0 = *(const uint4*)(gah);
  uint4 vah1 = *(const uint4*)(gah + 8);
  const float* gx0 = x + xb + (long)kp*N_SP + n0 + nq;
  float4 vx00 = *(const float4*)(gx0);
  float4 vx01 = *(const float4*)(gx0 + 4);
  float4 vx10 = *(const float4*)(gx0 + N_SP);
  float4 vx11 = *(const float4*)(gx0 + N_SP + 4);

  for(int kk=0; kk<C_CH; kk+=32){
    // stage A (pure copy, full 32-col coverage) + B (cvt fp32->fp16)
    int ao = arow*LSTR + akh;
    *(uint4*)&As[ao] = vah0; *(uint4*)&As[ao + 8] = vah1;
    float f0[8] = {vx00.x,vx00.y,vx00.z,vx00.w, vx01.x,vx01.y,vx01.z,vx01.w};
    float f1[8] = {vx10.x,vx10.y,vx10.z,vx10.w, vx11.x,vx11.y,vx11.z,vx11.w};
    #pragma unroll
    for(int j=0;j<8;j++){
      u32 pk = (u32)f2h(f0[j]) | ((u32)f2h(f1[j]) << 16);
      *(u32*)&Bs[(nq + j)*LSTR + kp] = pk;
    }
    __syncthreads();
    // hoisted prefetch of next k-tile: overlaps ds_read + MFMA below
    if(kk + 32 < C_CH){
      vah0 = *(const uint4*)(gah + kk + 32);
      vah1 = *(const uint4*)(gah + kk + 32 + 8);
      const float* gxn = x + xb + (long)(kk + 32 + kp)*N_SP + n0 + nq;
      vx00 = *(const float4*)(gxn);
      vx01 = *(const float4*)(gxn + 4);
      vx10 = *(const float4*)(gxn + N_SP);
      vx11 = *(const float4*)(gxn + N_SP + 4);
    }
    f16x8 af[4], bf[4];
    #pragma unroll
    for(int mt=0; mt<4; mt++){
      int o = (wm*64 + mt*16 + lr)*LSTR + quad*8;
      af[mt] = *(const f16x8*)&As[o];
    }
    #pragma unroll
    for(int nt=0; nt<4; nt++){
      int o = (wn*64 + nt*16 + lr)*LSTR + quad*8;
      bf[nt] = *(const f16x8*)&Bs[o];
    }
    #pragma unroll
    for(int mt=0; mt<4; mt++)
      #pragma unroll
      for(int nt=0; nt<4; nt++)
        acc[mt][nt] = __builtin_amdgcn_mfma_f32_16x16x32_f16(af[mt], bf[nt], acc[mt][nt], 0, 0, 0);
    __syncthreads();   // readers done before next write
  }
  #pragma unroll
  for(int mt=0; mt<4; mt++){
    int mbase = m0 + wm*64 + mt*16 + quad*4;
    float cfv[4];
    #pragma unroll
    for(int r=0;r<4;r++) cfv[r] = cf[b*C_CH + mbase + r];
    #pragma unroll
    for(int nt=0; nt<4; nt++){
      int n = n0 + wn*64 + nt*16 + lr;
      #pragma unroll
      for(int r=0;r<4;r++){
        long idx = xb + (long)(mbase + r)*N_SP + n;
        y[idx] = acc[mt][nt][r] + x[idx] + cfv[r];
      }
    }
  }
}

extern "C" void kernel_launch(void* const* d_in, const int* in_sizes, int n_in,
                              void* d_out, int out_size, void* d_ws, size_t ws_size,
                              hipStream_t stream){
  const float* x    = (const float*)d_in[0];
  const float* gnw  = (const float*)d_in[1];
  const float* gnb  = (const float*)d_in[2];
  const float* qkvw = (const float*)d_in[3];
  const float* qkvb = (const float*)d_in[4];
  const float* pw   = (const float*)d_in[5];
  const float* pb   = (const float*)d_in[6];
  float* y = (float*)d_out;

  // --- scratch region A: front of d_out (chain done before k_final) --------
  char* w = (char*)d_out;
  size_t off = 0;
  auto alloc = [&](size_t bytes)->void*{
    void* p = w + off; off = (off + bytes + 255) & ~(size_t)255; return p;
  };
  float* GP   = (float*)alloc((size_t)NB*16*KSPLIT*16384*4); // 64 MB partial tiles
  float* G    = (float*)alloc((size_t)NB*C_CH*C_CH*4);
  float* T1   = (float*)alloc((size_t)NB*C_CH*C_CH*4);
  float* ATT  = (float*)alloc((size_t)NB*C_CH*C_CH*4);
  float* M0   = (float*)alloc((size_t)NB*C_CH*C_CH*4);
  float* AM   = (float*)alloc((size_t)NB*C_CH*C_CH*4);
  // 64 MB + ~10 MB << 128 MB d_out

  // --- scratch region B: d_ws — only what k_final reads (~1.2 MB) ----------
  char* w2 = (char*)d_ws;
  size_t off2 = 0;
  auto alloc2 = [&](size_t bytes)->void*{
    void* p = w2 + off2; off2 = (off2 + bytes + 255) & ~(size_t)255; return p;
  };
  u16*   AF16 = (u16*)  alloc2((size_t)NB*C_CH*C_CH*2);  // 1 MB (fp16 Af)
  float* CF   = (float*)alloc2(NB*C_CH*4);
  float* CS   = (float*)alloc2(NB*C_CH*4);
  float* CQ   = (float*)alloc2(NB*C_CH*4);
  float* S_   = (float*)alloc2(NB*C_CH*4);
  float* T_   = (float*)alloc2(NB*C_CH*4);
  float* RXN  = (float*)alloc2(NB*C_CH*4);
  float* AQ   = (float*)alloc2(NB*C_CH*4);
  float* AK   = (float*)alloc2(NB*C_CH*4);
  float* E    = (float*)alloc2(NB*C_CH*4);
  (void)ws_size; (void)in_sizes; (void)n_in; (void)out_size;

  const float scale = 0.04419417382415922f; // 1/sqrt(512)

  k_stats<<<NB*C_CH, 256, 0, stream>>>(x, CS, CQ);
  k_gn<<<4, 256, 0, stream>>>(CS, CQ, gnw, gnb, S_, T_, RXN);
  k_gram<<<dim3(16, KSPLIT, NB), 256, 0, stream>>>(x, GP);
  k_G<<<512, 256, 0, stream>>>(GP, S_, T_, CS, G);
  k_mm_nn<<<dim3(64,1,NB), 256, 0, stream>>>(qkvw, 0, G, 262144, T1, 262144);
  k_rowdot<<<dim3(512,NB), 128, 0, stream>>>(qkvw,          0, RXN, 512, AQ, 512, nullptr, 0, 0);
  k_rowdot<<<dim3(512,NB), 128, 0, stream>>>(qkvw+262144,   0, RXN, 512, AK, 512, nullptr, 0, 0);
  k_mm_nt_logits<<<dim3(64,1,NB), 256, 0, stream>>>(T1, 262144, qkvw+262144, ATT, 262144,
                                                    AQ, AK, qkvb, qkvb+512, scale);
  k_softmax<<<NB*C_CH, 256, 0, stream>>>(ATT);
  k_rowdot<<<dim3(512,NB), 128, 0, stream>>>(ATT, 262144, qkvb+1024, 0, E, 512, nullptr, 0, 0);
  k_mm_nn<<<dim3(64,1,NB), 256, 0, stream>>>(ATT, 262144, qkvw+524288, 0, M0, 262144);
  k_mm_nn<<<dim3(64,1,NB), 256, 0, stream>>>(pw, 0, M0, 262144, AM, 262144);
  k_rowdot<<<dim3(512,NB), 128, 0, stream>>>(AM, 262144, T_, 512, CF, 512, nullptr, 0, 0);
  k_rowdot<<<dim3(512,NB), 128, 0, stream>>>(pw, 0, E, 512, CF, 512, pb, 0, 1);
  k_af<<<(NB*C_CH*C_CH)/256, 256, 0, stream>>>(AM, S_, AF16);
  k_final<<<dim3(N_SP/128, C_CH/128, NB), 256, 0, stream>>>(AF16, x, CF, y);
}

// Round 9
// 598.378 us; speedup vs baseline: 1.1565x; 1.0259x over previous
//
#include <hip/hip_runtime.h>
#include <cstdint>

// AttentionBlock (fp32 I/O), algebraically collapsed:
//  xn = s*x + t (GroupNorm affine per batch/channel)
//  logits = scale*(Wq G Wk^T + aq bk^T + bq (ak + N bk)^T), G from Gx = x x^T
//  attn = softmax(logits);  y = x + Af x + cf 1^T,  Af = (Pw attn Wv) diag(s)
// k_gram uses split-bf16 (hi+lo, 3 products) — K=32768 demands ~2^-16 rel err.
// k_final uses SINGLE fp16 product — K=512, |Af|~0.05: err ~1e-3 << budget.
// R1: k_gram atomic-free, private partial tiles, reduction fused into k_G.
// R3: T14 reg-staged prefetch hoist in k_gram (kept).
// R6/R7: k_final fp16 single-product (162 -> <145 us, absmax unchanged).
// R8: k_gram: (a) uint4 conflict-free LDS writes (5-stagger, was 16.8M confl),
//     (b) trunc-hi pair-packed split (~35% less split VALU, err 2^-17/elem),
//     (c) XCD-aware remap: 16 tiles of one (ks,b) group -> one XCD (L2 reuse).
// R9: identical resubmit (R8 bench was an infra flake; kernel never measured).

typedef unsigned short u16;
typedef unsigned int u32;
typedef __bf16 bf16x8 __attribute__((ext_vector_type(8)));
typedef _Float16 f16x8 __attribute__((ext_vector_type(8)));
typedef float f4 __attribute__((ext_vector_type(4)));

#define N_SP 32768
#define C_CH 512
#define NB 2
#define KSPLIT 32
#define LSTR 40   // LDS row stride in u16 (16B-aligned rows)

__device__ __forceinline__ float b2f(u16 h){
  union { float f; u32 u; } v; v.u = ((u32)h) << 16; return v.f;
}
__device__ __forceinline__ u16 f2b(float f){
  union { float f; u32 u; } v; v.f = f;
  u32 u = v.u;
  return (u16)((u + 0x7fffu + ((u >> 16) & 1u)) >> 16);
}
__device__ __forceinline__ u16 f2h(float f){
  _Float16 h = (_Float16)f;
  union { _Float16 h; u16 u; } v; v.h = h; return v.u;
}
// trunc-hi split of two floats -> packed bf16 hi pair + RNE bf16 lo pair.
// hi = top16(v) (exact residual); lo = RNE(v - hi). |(hi+lo)-v| <= 2^-17|v|.
__device__ __forceinline__ void split2(float v0, float v1, u32& hi, u32& lo){
  union { float f; u32 u; } a, b; a.f = v0; b.f = v1;
  u32 h0 = a.u & 0xFFFF0000u, h1 = b.u & 0xFFFF0000u;
  hi = (a.u >> 16) | h1;
  union { u32 u; float f; } fh0, fh1; fh0.u = h0; fh1.u = h1;
  union { float f; u32 u; } r0, r1;
  r0.f = v0 - fh0.f;
  r1.f = v1 - fh1.f;
  lo = ((r0.u + 0x7fffu + ((r0.u >> 16) & 1u)) >> 16)
     | ((r1.u + 0x7fffu + ((r1.u >> 16) & 1u)) & 0xFFFF0000u);
}

// ---- per-channel sum / sumsq over N_SP (fp32 input) ------------------------
__global__ __launch_bounds__(256) void k_stats(const float* __restrict__ x,
                                               float* __restrict__ cs, float* __restrict__ cq){
  const long bc = blockIdx.x;                 // 0..NB*C_CH-1
  const float* p = x + bc * (long)N_SP;
  const int t = threadIdx.x;
  float s = 0.f, q = 0.f;
  for(int i=0;i<32;i++){
    float4 v = *(const float4*)(p + i*1024 + t*4);
    s += v.x + v.y + v.z + v.w;
    q += v.x*v.x + v.y*v.y + v.z*v.z + v.w*v.w;
  }
  for(int off=32; off; off>>=1){ s += __shfl_down(s, off, 64); q += __shfl_down(q, off, 64); }
  __shared__ float rs[4], rq[4];
  int lane = t & 63, wv = t >> 6;
  if(lane==0){ rs[wv]=s; rq[wv]=q; }
  __syncthreads();
  if(t==0){ cs[bc] = rs[0]+rs[1]+rs[2]+rs[3]; cq[bc] = rq[0]+rq[1]+rq[2]+rq[3]; }
}

// ---- group stats -> per-channel scale/shift + xn row-sums ------------------
__global__ void k_gn(const float* __restrict__ cs, const float* __restrict__ cq,
                     const float* __restrict__ gw, const float* __restrict__ gb,
                     float* __restrict__ s_, float* __restrict__ t_, float* __restrict__ rxn){
  int i = blockIdx.x*blockDim.x + threadIdx.x;
  if(i >= NB*C_CH) return;
  int b = i >> 9, c = i & 511, g = c >> 4;   // 512/32 = 16 channels per group
  int base = (b << 9) | (g << 4);
  float sum=0.f, sq=0.f;
  for(int j=0;j<16;j++){ sum += cs[base+j]; sq += cq[base+j]; }
  const float inv = 1.0f / (16.0f * (float)N_SP);
  float mean = sum * inv;
  float var = sq * inv - mean*mean;
  if(var < 0.f) var = 0.f;
  float rs = rsqrtf(var + 1e-5f);
  float sc = gw[c] * rs;
  float tt = gb[c] - mean * sc;
  s_[i] = sc; t_[i] = tt;
  rxn[i] = sc * cs[i] + (float)N_SP * tt;
}

// ---- Gram partials: Gp[b][tile][ks] = x_tile_i @ x_tile_j^T (no atomics) ---
__global__ __launch_bounds__(256) void k_gram(const float* __restrict__ x, float* __restrict__ Gp){
  __shared__ u16 Ah[128*LSTR], Al[128*LSTR], Bh[128*LSTR], Bl[128*LSTR];
  const int t = threadIdx.x;
  // XCD-aware remap: flat%8 = XCD (round-robin dispatch); give all 16 tiles
  // of one (ks,b) slice-group the same flat%8 so their 8x k-slice reuse is
  // served by that XCD's L2 instead of HBM/L3.
  const int flat = blockIdx.x + (blockIdx.y << 4) + (blockIdx.z << 9); // 0..1023
  const int xcd  = flat & 7;
  const int q    = flat >> 3;                 // 0..127
  const int g    = ((q >> 4) << 3) | xcd;     // slice group 0..63
  const int tile = q & 15;                    // 0..15 : ti*4 + tj
  const int ks   = g & 31;
  const int b    = g >> 5;
  const int ti = tile >> 2, tj = tile & 3;
  const int i0 = ti << 7, j0 = tj << 7;
  const long xb = (long)b * C_CH * (long)N_SP;
  const int k0 = ks * (N_SP / KSPLIT);
  const int lane = t & 63, wave = t >> 6;
  const int wm = wave >> 1, wn = wave & 1;
  const int lr = lane & 15, quad = lane >> 4;
  const int srow = t >> 1, skh = (t & 1) << 4;

  f4 acc[4][4];
  for(int i=0;i<4;i++) for(int j=0;j<4;j++){ f4 z = {0.f,0.f,0.f,0.f}; acc[i][j]=z; }

  const float* gi = x + xb + (long)(i0 + srow)*N_SP + k0 + skh;
  const float* gj = x + xb + (long)(j0 + srow)*N_SP + k0 + skh;

  // prologue: tile kk=0 into regs
  float4 va[4], vb[4];
  #pragma unroll
  for(int j2=0;j2<4;j2++){ va[j2] = *(const float4*)(gi + j2*4); vb[j2] = *(const float4*)(gj + j2*4); }

  for(int kk=0; kk<N_SP/KSPLIT; kk+=32){
    // trunc-hi pair-packed split (reg) then conflict-free uint4 LDS stores:
    // 16B slot index = 5*srow + 2*(t&1) + u mod 8 -> uniform 8 lanes/slot.
    u32 pha[8], pla[8], phb[8], plb[8];
    #pragma unroll
    for(int j2=0;j2<4;j2++){
      split2(va[j2].x, va[j2].y, pha[j2*2],   pla[j2*2]);
      split2(va[j2].z, va[j2].w, pha[j2*2+1], pla[j2*2+1]);
      split2(vb[j2].x, vb[j2].y, phb[j2*2],   plb[j2*2]);
      split2(vb[j2].z, vb[j2].w, phb[j2*2+1], plb[j2*2+1]);
    }
    int o = srow*LSTR + skh;
    *(uint4*)&Ah[o]   = *(const uint4*)&pha[0];
    *(uint4*)&Ah[o+8] = *(const uint4*)&pha[4];
    *(uint4*)&Al[o]   = *(const uint4*)&pla[0];
    *(uint4*)&Al[o+8] = *(const uint4*)&pla[4];
    *(uint4*)&Bh[o]   = *(const uint4*)&phb[0];
    *(uint4*)&Bh[o+8] = *(const uint4*)&phb[4];
    *(uint4*)&Bl[o]   = *(const uint4*)&plb[0];
    *(uint4*)&Bl[o+8] = *(const uint4*)&plb[4];
    __syncthreads();
    // hoisted prefetch: next tile's loads overlap ds_read+MFMA below
    if(kk + 32 < N_SP/KSPLIT){
      #pragma unroll
      for(int j2=0;j2<4;j2++){
        va[j2] = *(const float4*)(gi + kk + 32 + j2*4);
        vb[j2] = *(const float4*)(gj + kk + 32 + j2*4);
      }
    }
    bf16x8 ah[4], al[4], bh[4], bl[4];
    #pragma unroll
    for(int mt=0; mt<4; mt++){
      int o2 = (wm*64 + mt*16 + lr)*LSTR + quad*8;
      ah[mt] = *(const bf16x8*)&Ah[o2]; al[mt] = *(const bf16x8*)&Al[o2];
    }
    #pragma unroll
    for(int nt=0; nt<4; nt++){
      int o2 = (wn*64 + nt*16 + lr)*LSTR + quad*8;
      bh[nt] = *(const bf16x8*)&Bh[o2]; bl[nt] = *(const bf16x8*)&Bl[o2];
    }
    #pragma unroll
    for(int mt=0; mt<4; mt++)
      #pragma unroll
      for(int nt=0; nt<4; nt++){
        acc[mt][nt] = __builtin_amdgcn_mfma_f32_16x16x32_bf16(ah[mt], bh[nt], acc[mt][nt], 0, 0, 0);
        acc[mt][nt] = __builtin_amdgcn_mfma_f32_16x16x32_bf16(ah[mt], bl[nt], acc[mt][nt], 0, 0, 0);
        acc[mt][nt] = __builtin_amdgcn_mfma_f32_16x16x32_bf16(al[mt], bh[nt], acc[mt][nt], 0, 0, 0);
      }
    __syncthreads();   // readers done before next write
  }
  // coalesced private-partial store: Gp[((b*16+tile)*KSPLIT+ks)][128][128]
  float* dst = Gp + ((long)(b*16 + tile)*KSPLIT + ks) * 16384;
  #pragma unroll
  for(int mt=0; mt<4; mt++){
    #pragma unroll
    for(int nt=0; nt<4; nt++){
      int m = wm*64 + mt*16 + quad*4;
      int n = wn*64 + nt*16 + lr;
      #pragma unroll
      for(int r=0;r<4;r++)
        dst[(m + r)*128 + n] = acc[mt][nt][r];
    }
  }
}

// ---- reduce partials + apply GN affine to Gram -----------------------------
__global__ __launch_bounds__(256) void k_G(const float* __restrict__ Gp, const float* __restrict__ s_,
                                           const float* __restrict__ t_, const float* __restrict__ cs,
                                           float* __restrict__ G){
  long idx4 = ((long)blockIdx.x*256 + threadIdx.x) * 4;   // first of 4 consecutive elements
  int j = (int)(idx4 & 511);
  int i = (int)((idx4 >> 9) & 511);
  int b = (int)(idx4 >> 18);
  int tile = ((i >> 7) << 2) | (j >> 7);
  int il = i & 127, jl = j & 127;
  const float* src = Gp + ((long)(b*16 + tile)*KSPLIT) * 16384 + il*128 + jl;
  float ax=0.f, ay=0.f, az=0.f, aw=0.f;
  #pragma unroll 4
  for(int ks=0; ks<KSPLIT; ks++){
    float4 v = *(const float4*)(src + (long)ks*16384);
    ax += v.x; ay += v.y; az += v.z; aw += v.w;
  }
  long bo = (long)b << 9;
  float si = s_[bo+i], tii = t_[bo+i], csi = cs[bo+i];
  float g[4] = {ax, ay, az, aw};
  float4 out;
  float* po = (float*)&out;
  #pragma unroll
  for(int e=0;e<4;e++){
    int je = j + e;
    float sj = s_[bo+je], tj = t_[bo+je], csj = cs[bo+je];
    po[e] = si*sj*g[e] + si*csi*tj + tii*sj*csj + (float)N_SP*tii*tj;
  }
  *(float4*)&G[idx4] = out;
}

// ---- small fp32 matmuls, 512x512x512, C = A @ B ----------------------------
__global__ __launch_bounds__(256) void k_mm_nn(const float* __restrict__ A, long sA,
                                               const float* __restrict__ B, long sB,
                                               float* __restrict__ C, long sC){
  __shared__ float As_[16][68];
  __shared__ float Bs_[16][68];
  const int b = blockIdx.z;
  A += (long)b*sA; B += (long)b*sB; C += (long)b*sC;
  const int m0 = (blockIdx.x >> 3) << 6;
  const int n0 = (blockIdx.x & 7) << 6;
  const int t = threadIdx.x;
  const int tm = t >> 4, tn = t & 15;
  float acc[4][4] = {};
  const int ar = t >> 2, ac = (t & 3) << 2;
  const int br = t >> 4, bc = (t & 15) << 2;
  for(int k0=0; k0<512; k0+=16){
    float4 av = *(const float4*)&A[(long)(m0 + ar)*512 + k0 + ac];
    float4 bv = *(const float4*)&B[(long)(k0 + br)*512 + n0 + bc];
    __syncthreads();
    As_[ac+0][ar] = av.x; As_[ac+1][ar] = av.y; As_[ac+2][ar] = av.z; As_[ac+3][ar] = av.w;
    *(float4*)&Bs_[br][bc] = bv;
    __syncthreads();
    #pragma unroll
    for(int k=0;k<16;k++){
      float4 a4 = *(const float4*)&As_[k][tm<<2];
      float4 b4 = *(const float4*)&Bs_[k][tn<<2];
      float aa[4] = {a4.x,a4.y,a4.z,a4.w}, bb[4] = {b4.x,b4.y,b4.z,b4.w};
      #pragma unroll
      for(int i=0;i<4;i++)
        #pragma unroll
        for(int j=0;j<4;j++) acc[i][j] += aa[i]*bb[j];
    }
  }
  for(int i=0;i<4;i++) for(int j=0;j<4;j++)
    C[(long)(m0 + (tm<<2) + i)*512 + n0 + (tn<<2) + j] = acc[i][j];
}

// ---- logits: C = scale*(A @ Bn^T + aq bk^T + bq (ak + N bk)^T) -------------
__global__ __launch_bounds__(256) void k_mm_nt_logits(const float* __restrict__ A, long sA,
    const float* __restrict__ Bn, float* __restrict__ C, long sC,
    const float* __restrict__ aq, const float* __restrict__ ak,
    const float* __restrict__ bq, const float* __restrict__ bk, float scale){
  __shared__ float As_[16][68];
  __shared__ float Bs_[16][68];
  const int b = blockIdx.z;
  A += (long)b*sA; C += (long)b*sC;
  const float* aqb = aq + (long)b*512;
  const float* akb = ak + (long)b*512;
  const int m0 = (blockIdx.x >> 3) << 6;
  const int n0 = (blockIdx.x & 7) << 6;
  const int t = threadIdx.x;
  const int tm = t >> 4, tn = t & 15;
  float acc[4][4] = {};
  const int ar = t >> 2, ac = (t & 3) << 2;
  for(int k0=0; k0<512; k0+=16){
    float4 av = *(const float4*)&A[(long)(m0 + ar)*512 + k0 + ac];
    float4 bv = *(const float4*)&Bn[(long)(n0 + ar)*512 + k0 + ac];
    __syncthreads();
    As_[ac+0][ar] = av.x; As_[ac+1][ar] = av.y; As_[ac+2][ar] = av.z; As_[ac+3][ar] = av.w;
    Bs_[ac+0][ar] = bv.x; Bs_[ac+1][ar] = bv.y; Bs_[ac+2][ar] = bv.z; Bs_[ac+3][ar] = bv.w;
    __syncthreads();
    #pragma unroll
    for(int k=0;k<16;k++){
      float4 a4 = *(const float4*)&As_[k][tm<<2];
      float4 b4 = *(const float4*)&Bs_[k][tn<<2];
      float aa[4] = {a4.x,a4.y,a4.z,a4.w}, bb[4] = {b4.x,b4.y,b4.z,b4.w};
      #pragma unroll
      for(int i=0;i<4;i++)
        #pragma unroll
        for(int j=0;j<4;j++) acc[i][j] += aa[i]*bb[j];
    }
  }
  for(int i=0;i<4;i++) for(int j=0;j<4;j++){
    int gi = m0 + (tm<<2) + i, gj = n0 + (tn<<2) + j;
    float vv = acc[i][j] + aqb[gi]*bk[gj] + bq[gi]*(akb[gj] + (float)N_SP*bk[gj]);
    C[(long)gi*512 + gj] = scale*vv;
  }
}

// ---- row softmax over 512 --------------------------------------------------
__global__ __launch_bounds__(256) void k_softmax(float* __restrict__ L){
  const long row = blockIdx.x;
  float* p = L + row*512;
  const int t = threadIdx.x;
  float v0 = p[t], v1 = p[t+256];
  float m = fmaxf(v0, v1);
  for(int off=32; off; off>>=1) m = fmaxf(m, __shfl_down(m, off, 64));
  __shared__ float red[4], red2[4];
  int lane = t & 63, wv = t >> 6;
  if(lane==0) red[wv] = m;
  __syncthreads();
  float M = fmaxf(fmaxf(red[0],red[1]), fmaxf(red[2],red[3]));
  float e0 = __expf(v0 - M), e1 = __expf(v1 - M);
  float s = e0 + e1;
  for(int off=32; off; off>>=1) s += __shfl_down(s, off, 64);
  if(lane==0) red2[wv] = s;
  __syncthreads();
  float inv = 1.0f / (red2[0]+red2[1]+red2[2]+red2[3]);
  p[t] = e0*inv; p[t+256] = e1*inv;
}

// ---- out[b,i] = M[b] row_i . v[b] (+ addv) (+= out) ------------------------
__global__ __launch_bounds__(128) void k_rowdot(const float* __restrict__ M, long sM,
    const float* __restrict__ v, long sv, float* __restrict__ out, long sout,
    const float* __restrict__ addv, long saddv, int accum){
  const int i = blockIdx.x, b = blockIdx.y;
  const float* Mr = M + (long)b*sM + (long)i*512;
  const float* vb = v + (long)b*sv;
  const int t = threadIdx.x;
  float s = Mr[t]*vb[t] + Mr[t+128]*vb[t+128] + Mr[t+256]*vb[t+256] + Mr[t+384]*vb[t+384];
  for(int off=32; off; off>>=1) s += __shfl_down(s, off, 64);
  __shared__ float r2[2];
  if((t&63)==0) r2[t>>6] = s;
  __syncthreads();
  if(t==0){
    float r = r2[0] + r2[1];
    long oi = (long)b*sout + i;
    if(addv) r += addv[(long)b*saddv + i];
    if(accum) r += out[oi];
    out[oi] = r;
  }
}

// ---- Af = AM * diag(s) -> fp16 ---------------------------------------------
__global__ void k_af(const float* __restrict__ A, const float* __restrict__ s_,
                     u16* __restrict__ Af16){
  long idx = (long)blockIdx.x*256 + threadIdx.x;
  int k = idx & 511; long b = idx >> 18;
  float vv = A[idx] * s_[(b<<9) + k];
  Af16[idx] = f2h(vv);
}

// ---- final: y = x + Af @ x + cf 1^T  (single fp16 product, K=512) ----------
// 128x128 tile, 2x2 waves. Coalesced pairwise A loads (2 threads/row, 16 u16
// each = full 32-col tile). x converted to fp16 on the fly. Prefetch hoist.
__global__ __launch_bounds__(256) void k_final(const u16* __restrict__ Af16,
                                               const float* __restrict__ x, const float* __restrict__ cf,
                                               float* __restrict__ y){
  __shared__ u16 As[128*LSTR], Bs[128*LSTR];
  const int t = threadIdx.x;
  const int b = blockIdx.z;
  const int n0 = blockIdx.x << 7;
  const int m0 = blockIdx.y << 7;
  const int lane = t & 63, wave = t >> 6;
  const int wm = wave >> 1, wn = wave & 1;
  const int lr = lane & 15, quad = lane >> 4;
  // A staging: 2 threads/row; each covers 16 u16 (two uint4) -> 32 cols/row
  const int arow = t >> 1, akh = (t & 1) << 4;
  const long afb = (long)b*C_CH*C_CH;
  // B staging: thread owns k-pair (kp,kp+1) x 8 n
  const int kp = (t & 15) << 1;   // k row pair 0..30
  const int nq = (t >> 4) << 3;   // n group 0..120
  const long xb = (long)b*C_CH*(long)N_SP;

  f4 acc[4][4];
  for(int i=0;i<4;i++) for(int j=0;j<4;j++){ f4 z = {0.f,0.f,0.f,0.f}; acc[i][j]=z; }

  const u16* gah = Af16 + afb + (long)(m0 + arow)*C_CH + akh;
  // prologue: kk=0 into regs
  uint4 vah0 = *(const uint4*)(gah);
  uint4 vah1 = *(const uint4*)(gah + 8);
  const float* gx0 = x + xb + (long)kp*N_SP + n0 + nq;
  float4 vx00 = *(const float4*)(gx0);
  float4 vx01 = *(const float4*)(gx0 + 4);
  float4 vx10 = *(const float4*)(gx0 + N_SP);
  float4 vx11 = *(const float4*)(gx0 + N_SP + 4);

  for(int kk=0; kk<C_CH; kk+=32){
    // stage A (pure copy, full 32-col coverage) + B (cvt fp32->fp16)
    int ao = arow*LSTR + akh;
    *(uint4*)&As[ao] = vah0; *(uint4*)&As[ao + 8] = vah1;
    float f0[8] = {vx00.x,vx00.y,vx00.z,vx00.w, vx01.x,vx01.y,vx01.z,vx01.w};
    float f1[8] = {vx10.x,vx10.y,vx10.z,vx10.w, vx11.x,vx11.y,vx11.z,vx11.w};
    #pragma unroll
    for(int j=0;j<8;j++){
      u32 pk = (u32)f2h(f0[j]) | ((u32)f2h(f1[j]) << 16);
      *(u32*)&Bs[(nq + j)*LSTR + kp] = pk;
    }
    __syncthreads();
    // hoisted prefetch of next k-tile: overlaps ds_read + MFMA below
    if(kk + 32 < C_CH){
      vah0 = *(const uint4*)(gah + kk + 32);
      vah1 = *(const uint4*)(gah + kk + 32 + 8);
      const float* gxn = x + xb + (long)(kk + 32 + kp)*N_SP + n0 + nq;
      vx00 = *(const float4*)(gxn);
      vx01 = *(const float4*)(gxn + 4);
      vx10 = *(const float4*)(gxn + N_SP);
      vx11 = *(const float4*)(gxn + N_SP + 4);
    }
    f16x8 af[4], bf[4];
    #pragma unroll
    for(int mt=0; mt<4; mt++){
      int o = (wm*64 + mt*16 + lr)*LSTR + quad*8;
      af[mt] = *(const f16x8*)&As[o];
    }
    #pragma unroll
    for(int nt=0; nt<4; nt++){
      int o = (wn*64 + nt*16 + lr)*LSTR + quad*8;
      bf[nt] = *(const f16x8*)&Bs[o];
    }
    #pragma unroll
    for(int mt=0; mt<4; mt++)
      #pragma unroll
      for(int nt=0; nt<4; nt++)
        acc[mt][nt] = __builtin_amdgcn_mfma_f32_16x16x32_f16(af[mt], bf[nt], acc[mt][nt], 0, 0, 0);
    __syncthreads();   // readers done before next write
  }
  #pragma unroll
  for(int mt=0; mt<4; mt++){
    int mbase = m0 + wm*64 + mt*16 + quad*4;
    float cfv[4];
    #pragma unroll
    for(int r=0;r<4;r++) cfv[r] = cf[b*C_CH + mbase + r];
    #pragma unroll
    for(int nt=0; nt<4; nt++){
      int n = n0 + wn*64 + nt*16 + lr;
      #pragma unroll
      for(int r=0;r<4;r++){
        long idx = xb + (long)(mbase + r)*N_SP + n;
        y[idx] = acc[mt][nt][r] + x[idx] + cfv[r];
      }
    }
  }
}

extern "C" void kernel_launch(void* const* d_in, const int* in_sizes, int n_in,
                              void* d_out, int out_size, void* d_ws, size_t ws_size,
                              hipStream_t stream){
  const float* x    = (const float*)d_in[0];
  const float* gnw  = (const float*)d_in[1];
  const float* gnb  = (const float*)d_in[2];
  const float* qkvw = (const float*)d_in[3];
  const float* qkvb = (const float*)d_in[4];
  const float* pw   = (const float*)d_in[5];
  const float* pb   = (const float*)d_in[6];
  float* y = (float*)d_out;

  // --- scratch region A: front of d_out (chain done before k_final) --------
  char* w = (char*)d_out;
  size_t off = 0;
  auto alloc = [&](size_t bytes)->void*{
    void* p = w + off; off = (off + bytes + 255) & ~(size_t)255; return p;
  };
  float* GP   = (float*)alloc((size_t)NB*16*KSPLIT*16384*4); // 64 MB partial tiles
  float* G    = (float*)alloc((size_t)NB*C_CH*C_CH*4);
  float* T1   = (float*)alloc((size_t)NB*C_CH*C_CH*4);
  float* ATT  = (float*)alloc((size_t)NB*C_CH*C_CH*4);
  float* M0   = (float*)alloc((size_t)NB*C_CH*C_CH*4);
  float* AM   = (float*)alloc((size_t)NB*C_CH*C_CH*4);
  // 64 MB + ~10 MB << 128 MB d_out

  // --- scratch region B: d_ws — only what k_final reads (~1.2 MB) ----------
  char* w2 = (char*)d_ws;
  size_t off2 = 0;
  auto alloc2 = [&](size_t bytes)->void*{
    void* p = w2 + off2; off2 = (off2 + bytes + 255) & ~(size_t)255; return p;
  };
  u16*   AF16 = (u16*)  alloc2((size_t)NB*C_CH*C_CH*2);  // 1 MB (fp16 Af)
  float* CF   = (float*)alloc2(NB*C_CH*4);
  float* CS   = (float*)alloc2(NB*C_CH*4);
  float* CQ   = (float*)alloc2(NB*C_CH*4);
  float* S_   = (float*)alloc2(NB*C_CH*4);
  float* T_   = (float*)alloc2(NB*C_CH*4);
  float* RXN  = (float*)alloc2(NB*C_CH*4);
  float* AQ   = (float*)alloc2(NB*C_CH*4);
  float* AK   = (float*)alloc2(NB*C_CH*4);
  float* E    = (float*)alloc2(NB*C_CH*4);
  (void)ws_size; (void)in_sizes; (void)n_in; (void)out_size;

  const float scale = 0.04419417382415922f; // 1/sqrt(512)

  k_stats<<<NB*C_CH, 256, 0, stream>>>(x, CS, CQ);
  k_gn<<<4, 256, 0, stream>>>(CS, CQ, gnw, gnb, S_, T_, RXN);
  k_gram<<<dim3(16, KSPLIT, NB), 256, 0, stream>>>(x, GP);
  k_G<<<512, 256, 0, stream>>>(GP, S_, T_, CS, G);
  k_mm_nn<<<dim3(64,1,NB), 256, 0, stream>>>(qkvw, 0, G, 262144, T1, 262144);
  k_rowdot<<<dim3(512,NB), 128, 0, stream>>>(qkvw,          0, RXN, 512, AQ, 512, nullptr, 0, 0);
  k_rowdot<<<dim3(512,NB), 128, 0, stream>>>(qkvw+262144,   0, RXN, 512, AK, 512, nullptr, 0, 0);
  k_mm_nt_logits<<<dim3(64,1,NB), 256, 0, stream>>>(T1, 262144, qkvw+262144, ATT, 262144,
                                                    AQ, AK, qkvb, qkvb+512, scale);
  k_softmax<<<NB*C_CH, 256, 0, stream>>>(ATT);
  k_rowdot<<<dim3(512,NB), 128, 0, stream>>>(ATT, 262144, qkvb+1024, 0, E, 512, nullptr, 0, 0);
  k_mm_nn<<<dim3(64,1,NB), 256, 0, stream>>>(ATT, 262144, qkvw+524288, 0, M0, 262144);
  k_mm_nn<<<dim3(64,1,NB), 256, 0, stream>>>(pw, 0, M0, 262144, AM, 262144);
  k_rowdot<<<dim3(512,NB), 128, 0, stream>>>(AM, 262144, T_, 512, CF, 512, nullptr, 0, 0);
  k_rowdot<<<dim3(512,NB), 128, 0, stream>>>(pw, 0, E, 512, CF, 512, pb, 0, 1);
  k_af<<<(NB*C_CH*C_CH)/256, 256, 0, stream>>>(AM, S_, AF16);
  k_final<<<dim3(N_SP/128, C_CH/128, NB), 256, 0, stream>>>(AF16, x, CF, y);
}